// Round 1
// baseline (907.337 us; speedup 1.0000x reference)
//
#include <hip/hip_runtime.h>
#include <hip/hip_fp16.h>

// SparseConvolutionDownsample: rulebook sparse conv (gather -> GEMM -> scatter-add)
// + BatchNorm over active sites + LeakyReLU(0.333).
//
// Constants: C_IN=64, C_OUT=128, K=4, P=262144, n_out=262144.
//
// R4: GEMM moved to MFMA (v_mfma_f32_16x16x32_bf16). R3 counters showed
// MfmaUtil=0, VALUBusy=51% => half the kernel was fp32-VALU GEMM. Now:
//  - pre-kernel transposes W -> bf16 Wt[k][n][c] (64KB, L2-resident);
//    B-fragments load global->VGPR directly, no W LDS stage per block.
//  - feats tile staged bf16 in LDS with stride 72 (144B rows: <=2-way bank
//    aliasing for ds_read_b128 A-fragments).
//  - per-16-row-tile epilogue: shfl_xor(1) pairs adjacent-lane channels ->
//    same 32 pk_f16 atomics/thread as R3, spread through the kernel.
// Fallback to the R2 fp32 path if ws_size is too small.

#define C_IN   64
#define C_OUT  128
#define KOFF   4
#define TILE_P 128
#define SF_LD  72            // bf16 elems/row: 144B stride (16B-aligned, pad)
#define BN_EPS 1e-4f
#define LEAK   0.333f

typedef __attribute__((ext_vector_type(8))) short short8;
typedef __attribute__((ext_vector_type(4))) float f32x4;

__device__ inline unsigned short f32_to_bf16_rn(float x) {
    unsigned int b = __float_as_uint(x);
    unsigned int r = (b + 0x7FFFu + ((b >> 16) & 1u)) >> 16;
    return (unsigned short)r;
}

struct h2pair { __half2 a, b; };   // 8 B = 4 channels

// ===========================================================================
// Pre-kernel: W [K][C_IN][C_OUT] fp32 -> Wt [K][C_OUT][C_IN] bf16 (64 KB).
// ===========================================================================
__global__ __launch_bounds__(256) void build_wt_kernel(
    const float* __restrict__ W, unsigned short* __restrict__ Wt)
{
    const int k = blockIdx.x;          // 0..3
    const int t = threadIdx.x;         // 256
    const int n  = t >> 1;             // output channel 0..127
    const int c0 = (t & 1) * 32;       // input-channel half

    unsigned int buf[16];
    #pragma unroll
    for (int j = 0; j < 16; ++j) {
        int c = c0 + 2 * j;
        unsigned short lo = f32_to_bf16_rn(W[((size_t)k * C_IN + c) * C_OUT + n]);
        unsigned short hi = f32_to_bf16_rn(W[((size_t)k * C_IN + c + 1) * C_OUT + n]);
        buf[j] = (unsigned int)lo | ((unsigned int)hi << 16);
    }
    uint4* dst = (uint4*)(Wt + ((size_t)k * C_OUT + n) * C_IN + c0);
    dst[0] = make_uint4(buf[0],  buf[1],  buf[2],  buf[3]);
    dst[1] = make_uint4(buf[4],  buf[5],  buf[6],  buf[7]);
    dst[2] = make_uint4(buf[8],  buf[9],  buf[10], buf[11]);
    dst[3] = make_uint4(buf[12], buf[13], buf[14], buf[15]);
}

// ===========================================================================
// Kernel 1h (R4): gather + MFMA 128x128x64 tile + pk_add_f16 scatter.
// 4 waves/block; wave w owns cols 32w..32w+31 (2 col-tiles of 16).
// ===========================================================================
__global__ __launch_bounds__(256) void scatter_gemm_mfma_kernel(
    const float* __restrict__ feats, const unsigned short* __restrict__ Wt,
    const int* __restrict__ in_idx, const int* __restrict__ out_idx,
    __half2* __restrict__ outh, int P)
{
    __shared__ unsigned short sF[TILE_P][SF_LD];   // 18.4 KB bf16 feats tile
    __shared__ int sO[TILE_P];                     // out rows for this tile

    const int tid = threadIdx.x;
    const int k  = blockIdx.y;
    const int p0 = blockIdx.x * TILE_P;

    if (tid < TILE_P)
        sO[tid] = out_idx[(size_t)k * P + p0 + tid];

    // Stage gathered feats as bf16 into LDS (8 iters: row = i>>4, 4ch chunk = i&15).
    for (int i = tid; i < TILE_P * (C_IN / 4); i += 256) {
        int r  = i >> 4;
        int c4 = i & 15;
        int src = in_idx[(size_t)k * P + p0 + r];
        float4 v = ((const float4*)(feats + (size_t)src * C_IN))[c4];
        unsigned int lo = (unsigned int)f32_to_bf16_rn(v.x) | ((unsigned int)f32_to_bf16_rn(v.y) << 16);
        unsigned int hi = (unsigned int)f32_to_bf16_rn(v.z) | ((unsigned int)f32_to_bf16_rn(v.w) << 16);
        *(uint2*)&sF[r][c4 * 4] = make_uint2(lo, hi);
    }

    const int l  = tid & 63;
    const int w  = tid >> 6;        // wave id -> col base 32w
    const int lr = l & 15;          // A row / D col within 16
    const int lg = l >> 4;          // k-group (8 elems) / D row-group (4 rows)
    const bool odd = (lr & 1) != 0;

    // B fragments from global Wt (L2-resident): [ct][s]
    // B[k=32s+8lg+j][n=32w+16ct+lr] = Wt[k4][n][c], contiguous 16B in c.
    short8 bfr[2][2];
    {
        const unsigned short* wb = Wt + ((size_t)(k * C_OUT + 32 * w + lr)) * C_IN + 8 * lg;
        bfr[0][0] = *(const short8*)(wb);
        bfr[0][1] = *(const short8*)(wb + 32);
        bfr[1][0] = *(const short8*)(wb + 16 * C_IN);
        bfr[1][1] = *(const short8*)(wb + 16 * C_IN + 32);
    }

    __syncthreads();

    #pragma unroll
    for (int m = 0; m < 8; ++m) {
        const unsigned short* fp = &sF[16 * m + lr][8 * lg];
        short8 a0 = *(const short8*)fp;          // k = 8lg..8lg+7
        short8 a1 = *(const short8*)(fp + 32);   // k = 32+8lg..

        f32x4 acc0 = {0.f, 0.f, 0.f, 0.f};
        f32x4 acc1 = {0.f, 0.f, 0.f, 0.f};
        acc0 = __builtin_amdgcn_mfma_f32_16x16x32_bf16(a0, bfr[0][0], acc0, 0, 0, 0);
        acc0 = __builtin_amdgcn_mfma_f32_16x16x32_bf16(a1, bfr[0][1], acc0, 0, 0, 0);
        acc1 = __builtin_amdgcn_mfma_f32_16x16x32_bf16(a0, bfr[1][0], acc1, 0, 0, 0);
        acc1 = __builtin_amdgcn_mfma_f32_16x16x32_bf16(a1, bfr[1][1], acc1, 0, 0, 0);

        // Scatter tile m. D layout: row = 4*lg + reg, col = lr.
        // Pair adjacent lanes (cols 2a,2a+1) via shfl_xor(1):
        //   even lane writes row(+q),  pk = (self[q],   partner[q])
        //   odd  lane writes row(+q+1),pk = (partner[q+1], self[q+1])
        const int rbase = 16 * m + 4 * lg;
        const int cpair = 16 * w + ((lr & ~1) >> 1);   // __half2 index of col pair
        #pragma unroll
        for (int q = 0; q < 4; q += 2) {
            float va = acc0[q], vb = acc0[q + 1];
            float ta = __shfl_xor(va, 1);
            float tb = __shfl_xor(vb, 1);
            int row = sO[rbase + q + (odd ? 1 : 0)];
            __half2 h0 = odd ? __floats2half2_rn(tb, vb) : __floats2half2_rn(va, ta);
            __half2* op = outh + (size_t)row * (C_OUT / 2) + cpair;
            unsafeAtomicAdd(op, h0);

            float wa = acc1[q], wbv = acc1[q + 1];
            float ua = __shfl_xor(wa, 1);
            float ub = __shfl_xor(wbv, 1);
            __half2 h1 = odd ? __floats2half2_rn(ub, wbv) : __floats2half2_rn(wa, ua);
            unsafeAtomicAdd(op + 8, h1);   // cols +16 -> +8 __half2
        }
    }
}

// Kernel 2h: per-channel sum/sumsq over half accumulator.
__global__ __launch_bounds__(256) void bn_stats_half_kernel(
    const __half2* __restrict__ outh, float* __restrict__ stats, int n_out)
{
    const int tid = threadIdx.x;
    const int c4   = tid & 31;   // channels 4*c4 .. 4*c4+3
    const int rgrp = tid >> 5;   // 8 rows per block-iteration

    float4 s  = make_float4(0.f, 0.f, 0.f, 0.f);
    float4 s2 = make_float4(0.f, 0.f, 0.f, 0.f);
    for (int r = blockIdx.x * 8 + rgrp; r < n_out; r += gridDim.x * 8) {
        h2pair u = ((const h2pair*)(outh + (size_t)r * (C_OUT / 2)))[c4];
        float2 fa = __half22float2(u.a), fb = __half22float2(u.b);
        s.x += fa.x; s.y += fa.y; s.z += fb.x; s.w += fb.y;
        s2.x += fa.x * fa.x; s2.y += fa.y * fa.y; s2.z += fb.x * fb.x; s2.w += fb.y * fb.y;
    }

    __shared__ float4 red[256], red2[256];
    red[tid] = s; red2[tid] = s2;
    __syncthreads();
    if (tid < 32) {
        #pragma unroll
        for (int j = 1; j < 8; ++j) {
            float4 a = red[tid + 32 * j], b = red2[tid + 32 * j];
            s.x += a.x; s.y += a.y; s.z += a.z; s.w += a.w;
            s2.x += b.x; s2.y += b.y; s2.z += b.z; s2.w += b.w;
        }
        atomicAdd(&stats[4 * tid + 0], s.x);
        atomicAdd(&stats[4 * tid + 1], s.y);
        atomicAdd(&stats[4 * tid + 2], s.z);
        atomicAdd(&stats[4 * tid + 3], s.w);
        atomicAdd(&stats[C_OUT + 4 * tid + 0], s2.x);
        atomicAdd(&stats[C_OUT + 4 * tid + 1], s2.y);
        atomicAdd(&stats[C_OUT + 4 * tid + 2], s2.z);
        atomicAdd(&stats[C_OUT + 4 * tid + 3], s2.w);
    }
}

// Kernel 3h: normalize + LeakyReLU, half in -> fp32 out.
__global__ __launch_bounds__(256) void bn_apply_half_kernel(
    const __half2* __restrict__ outh, float* __restrict__ out,
    const float* __restrict__ stats,
    const float* __restrict__ gamma, const float* __restrict__ beta,
    int n_out, float inv_n)
{
    const size_t total = (size_t)n_out * (C_OUT / 4);   // h2pair units
    size_t i = (size_t)blockIdx.x * 256 + threadIdx.x;
    const int c = (int)(i & 31) * 4;

    float4 sc, sh;
    {
        float m0 = stats[c + 0] * inv_n, m1 = stats[c + 1] * inv_n,
              m2 = stats[c + 2] * inv_n, m3 = stats[c + 3] * inv_n;
        float v0 = stats[C_OUT + c + 0] * inv_n - m0 * m0;
        float v1 = stats[C_OUT + c + 1] * inv_n - m1 * m1;
        float v2 = stats[C_OUT + c + 2] * inv_n - m2 * m2;
        float v3 = stats[C_OUT + c + 3] * inv_n - m3 * m3;
        sc.x = gamma[c + 0] * rsqrtf(v0 + BN_EPS);
        sc.y = gamma[c + 1] * rsqrtf(v1 + BN_EPS);
        sc.z = gamma[c + 2] * rsqrtf(v2 + BN_EPS);
        sc.w = gamma[c + 3] * rsqrtf(v3 + BN_EPS);
        sh.x = beta[c + 0] - m0 * sc.x;
        sh.y = beta[c + 1] - m1 * sc.y;
        sh.z = beta[c + 2] - m2 * sc.z;
        sh.w = beta[c + 3] - m3 * sc.w;
    }

    const h2pair* ih = (const h2pair*)outh;
    float4* o4 = (float4*)out;
    for (; i < total; i += (size_t)gridDim.x * 256) {
        h2pair u = ih[i];
        float2 fa = __half22float2(u.a), fb = __half22float2(u.b);
        float4 v = make_float4(fa.x, fa.y, fb.x, fb.y);
        v.x = v.x * sc.x + sh.x; v.x = v.x >= 0.f ? v.x : LEAK * v.x;
        v.y = v.y * sc.y + sh.y; v.y = v.y >= 0.f ? v.y : LEAK * v.y;
        v.z = v.z * sc.z + sh.z; v.z = v.z >= 0.f ? v.z : LEAK * v.z;
        v.w = v.w * sc.w + sh.w; v.w = v.w >= 0.f ? v.w : LEAK * v.w;
        o4[i] = v;
    }
}

// ===========================================================================
// FP32 FALLBACK PATH (R2, unchanged) — used if ws_size too small
// ===========================================================================

__global__ __launch_bounds__(256) void scatter_gemm_f32_kernel(
    const float* __restrict__ feats, const float* __restrict__ W,
    const int* __restrict__ in_idx, const int* __restrict__ out_idx,
    float* __restrict__ out, int P)
{
    __shared__ float sW[C_IN][C_OUT];
    __shared__ unsigned short sF[TILE_P][66];

    const int tid = threadIdx.x;
    const int k  = blockIdx.y;
    const int p0 = blockIdx.x * TILE_P;

    const float4* Wk4 = (const float4*)(W + (size_t)k * C_IN * C_OUT);
    float4* sW4 = (float4*)&sW[0][0];
    #pragma unroll
    for (int i = tid; i < C_IN * C_OUT / 4; i += 256)
        sW4[i] = Wk4[i];

    for (int i = tid; i < TILE_P * (C_IN / 4); i += 256) {
        int r  = i >> 4;
        int c4 = i & 15;
        int src = in_idx[(size_t)k * P + p0 + r];
        float4 v = ((const float4*)(feats + (size_t)src * C_IN))[c4];
        unsigned int lo = (unsigned int)f32_to_bf16_rn(v.x) | ((unsigned int)f32_to_bf16_rn(v.y) << 16);
        unsigned int hi = (unsigned int)f32_to_bf16_rn(v.z) | ((unsigned int)f32_to_bf16_rn(v.w) << 16);
        unsigned int* dst = (unsigned int*)&sF[r][c4 * 4];
        dst[0] = lo;
        dst[1] = hi;
    }
    __syncthreads();

    const int tx = tid & 15;
    const int ty = tid >> 4;

    float acc[8][8];
    #pragma unroll
    for (int r = 0; r < 8; ++r)
        #pragma unroll
        for (int j = 0; j < 8; ++j) acc[r][j] = 0.f;

    #pragma unroll 4
    for (int kk2 = 0; kk2 < C_IN / 2; ++kk2) {
        float w0[8], w1[8];
        #pragma unroll
        for (int j = 0; j < 8; ++j) {
            w0[j] = sW[2 * kk2 + 0][tx + 16 * j];
            w1[j] = sW[2 * kk2 + 1][tx + 16 * j];
        }
        float f0[8], f1[8];
        #pragma unroll
        for (int r = 0; r < 8; ++r) {
            unsigned int u = *(const unsigned int*)&sF[8 * ty + r][2 * kk2];
            f0[r] = __uint_as_float(u << 16);
            f1[r] = __uint_as_float(u & 0xFFFF0000u);
        }
        #pragma unroll
        for (int r = 0; r < 8; ++r)
            #pragma unroll
            for (int j = 0; j < 8; ++j) {
                acc[r][j] = fmaf(f0[r], w0[j], acc[r][j]);
                acc[r][j] = fmaf(f1[r], w1[j], acc[r][j]);
            }
    }

    #pragma unroll
    for (int r = 0; r < 8; ++r) {
        int orow = out_idx[(size_t)k * P + p0 + 8 * ty + r];
        float* op = out + (size_t)orow * C_OUT + tx;
        #pragma unroll
        for (int j = 0; j < 8; ++j)
            atomicAdd(op + 16 * j, acc[r][j]);
    }
}

__global__ __launch_bounds__(256) void bn_stats_f32_kernel(
    const float* __restrict__ out, float* __restrict__ stats, int n_out)
{
    const int tid = threadIdx.x;
    const int c4   = tid & 31;
    const int rgrp = tid >> 5;

    float4 s  = make_float4(0.f, 0.f, 0.f, 0.f);
    float4 s2 = make_float4(0.f, 0.f, 0.f, 0.f);
    for (int r = blockIdx.x * 8 + rgrp; r < n_out; r += gridDim.x * 8) {
        float4 v = ((const float4*)(out + (size_t)r * C_OUT))[c4];
        s.x += v.x; s.y += v.y; s.z += v.z; s.w += v.w;
        s2.x += v.x * v.x; s2.y += v.y * v.y; s2.z += v.z * v.z; s2.w += v.w * v.w;
    }

    __shared__ float4 red[256], red2[256];
    red[tid] = s; red2[tid] = s2;
    __syncthreads();
    if (tid < 32) {
        #pragma unroll
        for (int j = 1; j < 8; ++j) {
            float4 a = red[tid + 32 * j], b = red2[tid + 32 * j];
            s.x += a.x; s.y += a.y; s.z += a.z; s.w += a.w;
            s2.x += b.x; s2.y += b.y; s2.z += b.z; s2.w += b.w;
        }
        atomicAdd(&stats[4 * tid + 0], s.x);
        atomicAdd(&stats[4 * tid + 1], s.y);
        atomicAdd(&stats[4 * tid + 2], s.z);
        atomicAdd(&stats[4 * tid + 3], s.w);
        atomicAdd(&stats[C_OUT + 4 * tid + 0], s2.x);
        atomicAdd(&stats[C_OUT + 4 * tid + 1], s2.y);
        atomicAdd(&stats[C_OUT + 4 * tid + 2], s2.z);
        atomicAdd(&stats[C_OUT + 4 * tid + 3], s2.w);
    }
}

__global__ __launch_bounds__(256) void bn_apply_f32_kernel(
    float* __restrict__ out, const float* __restrict__ stats,
    const float* __restrict__ gamma, const float* __restrict__ beta,
    int n_out, float inv_n)
{
    const size_t total = (size_t)n_out * (C_OUT / 4);
    size_t i = (size_t)blockIdx.x * 256 + threadIdx.x;
    const int c = (int)(i & 31) * 4;

    float4 sc, sh;
    {
        float m0 = stats[c + 0] * inv_n, m1 = stats[c + 1] * inv_n,
              m2 = stats[c + 2] * inv_n, m3 = stats[c + 3] * inv_n;
        float v0 = stats[C_OUT + c + 0] * inv_n - m0 * m0;
        float v1 = stats[C_OUT + c + 1] * inv_n - m1 * m1;
        float v2 = stats[C_OUT + c + 2] * inv_n - m2 * m2;
        float v3 = stats[C_OUT + c + 3] * inv_n - m3 * m3;
        sc.x = gamma[c + 0] * rsqrtf(v0 + BN_EPS);
        sc.y = gamma[c + 1] * rsqrtf(v1 + BN_EPS);
        sc.z = gamma[c + 2] * rsqrtf(v2 + BN_EPS);
        sc.w = gamma[c + 3] * rsqrtf(v3 + BN_EPS);
        sh.x = beta[c + 0] - m0 * sc.x;
        sh.y = beta[c + 1] - m1 * sc.y;
        sh.z = beta[c + 2] - m2 * sc.z;
        sh.w = beta[c + 3] - m3 * sc.w;
    }

    float4* o4 = (float4*)out;
    for (; i < total; i += (size_t)gridDim.x * 256) {
        float4 v = o4[i];
        v.x = v.x * sc.x + sh.x; v.x = v.x >= 0.f ? v.x : LEAK * v.x;
        v.y = v.y * sc.y + sh.y; v.y = v.y >= 0.f ? v.y : LEAK * v.y;
        v.z = v.z * sc.z + sh.z; v.z = v.z >= 0.f ? v.z : LEAK * v.z;
        v.w = v.w * sc.w + sh.w; v.w = v.w >= 0.f ? v.w : LEAK * v.w;
        o4[i] = v;
    }
}

// ---------------------------------------------------------------------------
extern "C" void kernel_launch(void* const* d_in, const int* in_sizes, int n_in,
                              void* d_out, int out_size, void* d_ws, size_t ws_size,
                              hipStream_t stream)
{
    const float* feats  = (const float*)d_in[0];
    const float* W      = (const float*)d_in[1];
    const float* gamma  = (const float*)d_in[2];
    const float* beta   = (const float*)d_in[3];
    const int*  in_idx  = (const int*)d_in[4];
    const int*  out_idx = (const int*)d_in[5];

    const int P     = in_sizes[4] / KOFF;     // 262144
    const int n_out = out_size / C_OUT;       // 262144

    dim3 grid_g(P / TILE_P, KOFF);            // 2048 x 4

    const size_t half_bytes = (size_t)n_out * C_OUT * sizeof(__half);   // 67 MB
    const size_t wt_off     = (half_bytes + 1024 + 255) & ~(size_t)255;
    const size_t wt_bytes   = (size_t)KOFF * C_OUT * C_IN * sizeof(unsigned short); // 64 KB

    if (ws_size >= wt_off + wt_bytes) {
        __half2* outh = (__half2*)d_ws;
        float* stats = (float*)((char*)d_ws + half_bytes);
        unsigned short* Wt = (unsigned short*)((char*)d_ws + wt_off);

        hipMemsetAsync(d_ws, 0, half_bytes, stream);
        hipMemsetAsync(stats, 0, 2 * C_OUT * sizeof(float), stream);

        build_wt_kernel<<<KOFF, 256, 0, stream>>>(W, Wt);
        scatter_gemm_mfma_kernel<<<grid_g, 256, 0, stream>>>(feats, Wt, in_idx, out_idx, outh, P);
        bn_stats_half_kernel<<<1024, 256, 0, stream>>>(outh, stats, n_out);
        bn_apply_half_kernel<<<2048, 256, 0, stream>>>(outh, (float*)d_out, stats,
                                                       gamma, beta, n_out, 1.0f / n_out);
    } else {
        float* out   = (float*)d_out;
        float* stats = (float*)d_ws;
        hipMemsetAsync(d_out, 0, (size_t)out_size * sizeof(float), stream);
        hipMemsetAsync(d_ws, 0, 2 * C_OUT * sizeof(float), stream);

        scatter_gemm_f32_kernel<<<grid_g, 256, 0, stream>>>(feats, W, in_idx, out_idx, out, P);
        bn_stats_f32_kernel<<<1024, 256, 0, stream>>>(out, stats, n_out);
        bn_apply_f32_kernel<<<2048, 256, 0, stream>>>(out, stats, gamma, beta, n_out, 1.0f / n_out);
    }
}

// Round 2
// 699.562 us; speedup vs baseline: 1.2970x; 1.2970x over previous
//
#include <hip/hip_runtime.h>
#include <hip/hip_fp16.h>

// SparseConvolutionDownsample: rulebook sparse conv (gather -> GEMM -> scatter-add)
// + BatchNorm over active sites + LeakyReLU(0.333).
//
// Constants: C_IN=64, C_OUT=128, K=4, P=262144, n_out=262144.
//
// R5: 32x32x16 MFMA. R4 post-mortem: 16x16 D-layout (col=lane&15) gave only
// 32B-per-row atomic coverage -> 8M half-used 64B segments vs R3's 4M full
// segments -> atomic throughput halved (453us vs 333us with compute removed).
// 32x32 D-layout (col=lane&31) restores full 64B-per-row coverage per atomic
// instruction (4 rows x 64B, same as R3) while keeping the GEMM on MFMA.
// Also merged the two ws memsets into one dispatch.
// Fallback to the R2 fp32 path if ws_size is too small.

#define C_IN   64
#define C_OUT  128
#define KOFF   4
#define TILE_P 128
#define SF_LD  72            // bf16 elems/row: 144B stride (16B-aligned)
#define BN_EPS 1e-4f
#define LEAK   0.333f

typedef __attribute__((ext_vector_type(8)))  short short8;
typedef __attribute__((ext_vector_type(4)))  float f32x4;
typedef __attribute__((ext_vector_type(16))) float f32x16;

__device__ inline unsigned short f32_to_bf16_rn(float x) {
    unsigned int b = __float_as_uint(x);
    unsigned int r = (b + 0x7FFFu + ((b >> 16) & 1u)) >> 16;
    return (unsigned short)r;
}

struct h2pair { __half2 a, b; };   // 8 B = 4 channels

// ===========================================================================
// Pre-kernel: W [K][C_IN][C_OUT] fp32 -> Wt [K][C_OUT][C_IN] bf16 (64 KB).
// ===========================================================================
__global__ __launch_bounds__(256) void build_wt_kernel(
    const float* __restrict__ W, unsigned short* __restrict__ Wt)
{
    const int k = blockIdx.x;          // 0..3
    const int t = threadIdx.x;         // 256
    const int n  = t >> 1;             // output channel 0..127
    const int c0 = (t & 1) * 32;       // input-channel half

    unsigned int buf[16];
    #pragma unroll
    for (int j = 0; j < 16; ++j) {
        int c = c0 + 2 * j;
        unsigned short lo = f32_to_bf16_rn(W[((size_t)k * C_IN + c) * C_OUT + n]);
        unsigned short hi = f32_to_bf16_rn(W[((size_t)k * C_IN + c + 1) * C_OUT + n]);
        buf[j] = (unsigned int)lo | ((unsigned int)hi << 16);
    }
    uint4* dst = (uint4*)(Wt + ((size_t)k * C_OUT + n) * C_IN + c0);
    dst[0] = make_uint4(buf[0],  buf[1],  buf[2],  buf[3]);
    dst[1] = make_uint4(buf[4],  buf[5],  buf[6],  buf[7]);
    dst[2] = make_uint4(buf[8],  buf[9],  buf[10], buf[11]);
    dst[3] = make_uint4(buf[12], buf[13], buf[14], buf[15]);
}

// ===========================================================================
// Kernel 1h (R5): gather + 32x32x16 MFMA + full-segment pk_add_f16 scatter.
// 4 waves/block; wave w owns cols 32w..32w+31 (one 32-col tile), 4 row-tiles
// of 32. D layout: col = lane&31, row = (reg&3) + 8*(reg>>2) + 4*(lane>>5).
// ===========================================================================
__global__ __launch_bounds__(256) void scatter_gemm_mfma_kernel(
    const float* __restrict__ feats, const unsigned short* __restrict__ Wt,
    const int* __restrict__ in_idx, const int* __restrict__ out_idx,
    __half2* __restrict__ outh, int P)
{
    __shared__ unsigned short sF[TILE_P][SF_LD];   // 18.4 KB bf16 feats tile
    __shared__ int sO[TILE_P];                     // out rows for this tile

    const int tid = threadIdx.x;
    const int k  = blockIdx.y;
    const int p0 = blockIdx.x * TILE_P;

    if (tid < TILE_P)
        sO[tid] = out_idx[(size_t)k * P + p0 + tid];

    // Stage gathered feats as bf16 into LDS (8 iters: row = i>>4, 4ch chunk = i&15).
    for (int i = tid; i < TILE_P * (C_IN / 4); i += 256) {
        int r  = i >> 4;
        int c4 = i & 15;
        int src = in_idx[(size_t)k * P + p0 + r];
        float4 v = ((const float4*)(feats + (size_t)src * C_IN))[c4];
        unsigned int lo = (unsigned int)f32_to_bf16_rn(v.x) | ((unsigned int)f32_to_bf16_rn(v.y) << 16);
        unsigned int hi = (unsigned int)f32_to_bf16_rn(v.z) | ((unsigned int)f32_to_bf16_rn(v.w) << 16);
        *(uint2*)&sF[r][c4 * 4] = make_uint2(lo, hi);
    }

    const int l  = tid & 63;
    const int w  = tid >> 6;        // wave id -> col base 32w
    const int c  = l & 31;          // A row / B col / D col (2B units)
    const int hi = l >> 5;          // k-half selector; D row +4*hi
    const bool odd = (c & 1) != 0;
    const int cpair = 16 * w + (c >> 1);   // __half2 index of this lane's col pair

    // B fragments from global Wt (L2-resident), one per k-chunk of 16:
    // B[k=16s+8hi+j][n=32w+c] = Wt[k4][n][16s+8hi+j], contiguous 16B.
    short8 bfr[4];
    {
        const unsigned short* wb = Wt + ((size_t)(k * C_OUT + 32 * w + c)) * C_IN + 8 * hi;
        #pragma unroll
        for (int s = 0; s < 4; ++s)
            bfr[s] = *(const short8*)(wb + 16 * s);
    }

    __syncthreads();

    #pragma unroll
    for (int m = 0; m < 4; ++m) {
        f32x16 acc;
        #pragma unroll
        for (int j = 0; j < 16; ++j) acc[j] = 0.f;

        #pragma unroll
        for (int s = 0; s < 4; ++s) {
            // A[row=32m+c][k=16s+8hi+j]
            short8 a = *(const short8*)&sF[32 * m + c][16 * s + 8 * hi];
            acc = __builtin_amdgcn_mfma_f32_32x32x16_bf16(a, bfr[s], acc, 0, 0, 0);
        }

        // Scatter tile m. Pair regs (e,e+1) -> rows (R,R+1); pair adjacent
        // lanes via shfl_xor(1) so each lane holds one __half2 col pair:
        //   even lane: row R,   pk = (self[e],     partner[e])
        //   odd  lane: row R+1, pk = (partner[e+1], self[e+1])
        // Per atomic instr: 4 distinct rows, each covered 64B contiguously.
        #pragma unroll
        for (int e = 0; e < 16; e += 2) {
            const int rbase = 32 * m + (e & 3) + 8 * (e >> 2) + 4 * hi;
            float va = acc[e], vb = acc[e + 1];
            float ta = __shfl_xor(va, 1);
            float tb = __shfl_xor(vb, 1);
            int row = sO[rbase + (odd ? 1 : 0)];
            __half2 h = odd ? __floats2half2_rn(tb, vb) : __floats2half2_rn(va, ta);
            unsafeAtomicAdd(outh + (size_t)row * (C_OUT / 2) + cpair, h);
        }
    }
}

// Kernel 2h: per-channel sum/sumsq over half accumulator.
__global__ __launch_bounds__(256) void bn_stats_half_kernel(
    const __half2* __restrict__ outh, float* __restrict__ stats, int n_out)
{
    const int tid = threadIdx.x;
    const int c4   = tid & 31;   // channels 4*c4 .. 4*c4+3
    const int rgrp = tid >> 5;   // 8 rows per block-iteration

    float4 s  = make_float4(0.f, 0.f, 0.f, 0.f);
    float4 s2 = make_float4(0.f, 0.f, 0.f, 0.f);
    for (int r = blockIdx.x * 8 + rgrp; r < n_out; r += gridDim.x * 8) {
        h2pair u = ((const h2pair*)(outh + (size_t)r * (C_OUT / 2)))[c4];
        float2 fa = __half22float2(u.a), fb = __half22float2(u.b);
        s.x += fa.x; s.y += fa.y; s.z += fb.x; s.w += fb.y;
        s2.x += fa.x * fa.x; s2.y += fa.y * fa.y; s2.z += fb.x * fb.x; s2.w += fb.y * fb.y;
    }

    __shared__ float4 red[256], red2[256];
    red[tid] = s; red2[tid] = s2;
    __syncthreads();
    if (tid < 32) {
        #pragma unroll
        for (int j = 1; j < 8; ++j) {
            float4 a = red[tid + 32 * j], b = red2[tid + 32 * j];
            s.x += a.x; s.y += a.y; s.z += a.z; s.w += a.w;
            s2.x += b.x; s2.y += b.y; s2.z += b.z; s2.w += b.w;
        }
        atomicAdd(&stats[4 * tid + 0], s.x);
        atomicAdd(&stats[4 * tid + 1], s.y);
        atomicAdd(&stats[4 * tid + 2], s.z);
        atomicAdd(&stats[4 * tid + 3], s.w);
        atomicAdd(&stats[C_OUT + 4 * tid + 0], s2.x);
        atomicAdd(&stats[C_OUT + 4 * tid + 1], s2.y);
        atomicAdd(&stats[C_OUT + 4 * tid + 2], s2.z);
        atomicAdd(&stats[C_OUT + 4 * tid + 3], s2.w);
    }
}

// Kernel 3h: normalize + LeakyReLU, half in -> fp32 out.
__global__ __launch_bounds__(256) void bn_apply_half_kernel(
    const __half2* __restrict__ outh, float* __restrict__ out,
    const float* __restrict__ stats,
    const float* __restrict__ gamma, const float* __restrict__ beta,
    int n_out, float inv_n)
{
    const size_t total = (size_t)n_out * (C_OUT / 4);   // h2pair units
    size_t i = (size_t)blockIdx.x * 256 + threadIdx.x;
    const int c = (int)(i & 31) * 4;

    float4 sc, sh;
    {
        float m0 = stats[c + 0] * inv_n, m1 = stats[c + 1] * inv_n,
              m2 = stats[c + 2] * inv_n, m3 = stats[c + 3] * inv_n;
        float v0 = stats[C_OUT + c + 0] * inv_n - m0 * m0;
        float v1 = stats[C_OUT + c + 1] * inv_n - m1 * m1;
        float v2 = stats[C_OUT + c + 2] * inv_n - m2 * m2;
        float v3 = stats[C_OUT + c + 3] * inv_n - m3 * m3;
        sc.x = gamma[c + 0] * rsqrtf(v0 + BN_EPS);
        sc.y = gamma[c + 1] * rsqrtf(v1 + BN_EPS);
        sc.z = gamma[c + 2] * rsqrtf(v2 + BN_EPS);
        sc.w = gamma[c + 3] * rsqrtf(v3 + BN_EPS);
        sh.x = beta[c + 0] - m0 * sc.x;
        sh.y = beta[c + 1] - m1 * sc.y;
        sh.z = beta[c + 2] - m2 * sc.z;
        sh.w = beta[c + 3] - m3 * sc.w;
    }

    const h2pair* ih = (const h2pair*)outh;
    float4* o4 = (float4*)out;
    for (; i < total; i += (size_t)gridDim.x * 256) {
        h2pair u = ih[i];
        float2 fa = __half22float2(u.a), fb = __half22float2(u.b);
        float4 v = make_float4(fa.x, fa.y, fb.x, fb.y);
        v.x = v.x * sc.x + sh.x; v.x = v.x >= 0.f ? v.x : LEAK * v.x;
        v.y = v.y * sc.y + sh.y; v.y = v.y >= 0.f ? v.y : LEAK * v.y;
        v.z = v.z * sc.z + sh.z; v.z = v.z >= 0.f ? v.z : LEAK * v.z;
        v.w = v.w * sc.w + sh.w; v.w = v.w >= 0.f ? v.w : LEAK * v.w;
        o4[i] = v;
    }
}

// ===========================================================================
// FP32 FALLBACK PATH (R2, unchanged) — used if ws_size too small
// ===========================================================================

__global__ __launch_bounds__(256) void scatter_gemm_f32_kernel(
    const float* __restrict__ feats, const float* __restrict__ W,
    const int* __restrict__ in_idx, const int* __restrict__ out_idx,
    float* __restrict__ out, int P)
{
    __shared__ float sW[C_IN][C_OUT];
    __shared__ unsigned short sF[TILE_P][66];

    const int tid = threadIdx.x;
    const int k  = blockIdx.y;
    const int p0 = blockIdx.x * TILE_P;

    const float4* Wk4 = (const float4*)(W + (size_t)k * C_IN * C_OUT);
    float4* sW4 = (float4*)&sW[0][0];
    #pragma unroll
    for (int i = tid; i < C_IN * C_OUT / 4; i += 256)
        sW4[i] = Wk4[i];

    for (int i = tid; i < TILE_P * (C_IN / 4); i += 256) {
        int r  = i >> 4;
        int c4 = i & 15;
        int src = in_idx[(size_t)k * P + p0 + r];
        float4 v = ((const float4*)(feats + (size_t)src * C_IN))[c4];
        unsigned int lo = (unsigned int)f32_to_bf16_rn(v.x) | ((unsigned int)f32_to_bf16_rn(v.y) << 16);
        unsigned int hi = (unsigned int)f32_to_bf16_rn(v.z) | ((unsigned int)f32_to_bf16_rn(v.w) << 16);
        unsigned int* dst = (unsigned int*)&sF[r][c4 * 4];
        dst[0] = lo;
        dst[1] = hi;
    }
    __syncthreads();

    const int tx = tid & 15;
    const int ty = tid >> 4;

    float acc[8][8];
    #pragma unroll
    for (int r = 0; r < 8; ++r)
        #pragma unroll
        for (int j = 0; j < 8; ++j) acc[r][j] = 0.f;

    #pragma unroll 4
    for (int kk2 = 0; kk2 < C_IN / 2; ++kk2) {
        float w0[8], w1[8];
        #pragma unroll
        for (int j = 0; j < 8; ++j) {
            w0[j] = sW[2 * kk2 + 0][tx + 16 * j];
            w1[j] = sW[2 * kk2 + 1][tx + 16 * j];
        }
        float f0[8], f1[8];
        #pragma unroll
        for (int r = 0; r < 8; ++r) {
            unsigned int u = *(const unsigned int*)&sF[8 * ty + r][2 * kk2];
            f0[r] = __uint_as_float(u << 16);
            f1[r] = __uint_as_float(u & 0xFFFF0000u);
        }
        #pragma unroll
        for (int r = 0; r < 8; ++r)
            #pragma unroll
            for (int j = 0; j < 8; ++j) {
                acc[r][j] = fmaf(f0[r], w0[j], acc[r][j]);
                acc[r][j] = fmaf(f1[r], w1[j], acc[r][j]);
            }
    }

    #pragma unroll
    for (int r = 0; r < 8; ++r) {
        int orow = out_idx[(size_t)k * P + p0 + 8 * ty + r];
        float* op = out + (size_t)orow * C_OUT + tx;
        #pragma unroll
        for (int j = 0; j < 8; ++j)
            atomicAdd(op + 16 * j, acc[r][j]);
    }
}

__global__ __launch_bounds__(256) void bn_stats_f32_kernel(
    const float* __restrict__ out, float* __restrict__ stats, int n_out)
{
    const int tid = threadIdx.x;
    const int c4   = tid & 31;
    const int rgrp = tid >> 5;

    float4 s  = make_float4(0.f, 0.f, 0.f, 0.f);
    float4 s2 = make_float4(0.f, 0.f, 0.f, 0.f);
    for (int r = blockIdx.x * 8 + rgrp; r < n_out; r += gridDim.x * 8) {
        float4 v = ((const float4*)(out + (size_t)r * C_OUT))[c4];
        s.x += v.x; s.y += v.y; s.z += v.z; s.w += v.w;
        s2.x += v.x * v.x; s2.y += v.y * v.y; s2.z += v.z * v.z; s2.w += v.w * v.w;
    }

    __shared__ float4 red[256], red2[256];
    red[tid] = s; red2[tid] = s2;
    __syncthreads();
    if (tid < 32) {
        #pragma unroll
        for (int j = 1; j < 8; ++j) {
            float4 a = red[tid + 32 * j], b = red2[tid + 32 * j];
            s.x += a.x; s.y += a.y; s.z += a.z; s.w += a.w;
            s2.x += b.x; s2.y += b.y; s2.z += b.z; s2.w += b.w;
        }
        atomicAdd(&stats[4 * tid + 0], s.x);
        atomicAdd(&stats[4 * tid + 1], s.y);
        atomicAdd(&stats[4 * tid + 2], s.z);
        atomicAdd(&stats[4 * tid + 3], s.w);
        atomicAdd(&stats[C_OUT + 4 * tid + 0], s2.x);
        atomicAdd(&stats[C_OUT + 4 * tid + 1], s2.y);
        atomicAdd(&stats[C_OUT + 4 * tid + 2], s2.z);
        atomicAdd(&stats[C_OUT + 4 * tid + 3], s2.w);
    }
}

__global__ __launch_bounds__(256) void bn_apply_f32_kernel(
    float* __restrict__ out, const float* __restrict__ stats,
    const float* __restrict__ gamma, const float* __restrict__ beta,
    int n_out, float inv_n)
{
    const size_t total = (size_t)n_out * (C_OUT / 4);
    size_t i = (size_t)blockIdx.x * 256 + threadIdx.x;
    const int c = (int)(i & 31) * 4;

    float4 sc, sh;
    {
        float m0 = stats[c + 0] * inv_n, m1 = stats[c + 1] * inv_n,
              m2 = stats[c + 2] * inv_n, m3 = stats[c + 3] * inv_n;
        float v0 = stats[C_OUT + c + 0] * inv_n - m0 * m0;
        float v1 = stats[C_OUT + c + 1] * inv_n - m1 * m1;
        float v2 = stats[C_OUT + c + 2] * inv_n - m2 * m2;
        float v3 = stats[C_OUT + c + 3] * inv_n - m3 * m3;
        sc.x = gamma[c + 0] * rsqrtf(v0 + BN_EPS);
        sc.y = gamma[c + 1] * rsqrtf(v1 + BN_EPS);
        sc.z = gamma[c + 2] * rsqrtf(v2 + BN_EPS);
        sc.w = gamma[c + 3] * rsqrtf(v3 + BN_EPS);
        sh.x = beta[c + 0] - m0 * sc.x;
        sh.y = beta[c + 1] - m1 * sc.y;
        sh.z = beta[c + 2] - m2 * sc.z;
        sh.w = beta[c + 3] - m3 * sc.w;
    }

    float4* o4 = (float4*)out;
    for (; i < total; i += (size_t)gridDim.x * 256) {
        float4 v = o4[i];
        v.x = v.x * sc.x + sh.x; v.x = v.x >= 0.f ? v.x : LEAK * v.x;
        v.y = v.y * sc.y + sh.y; v.y = v.y >= 0.f ? v.y : LEAK * v.y;
        v.z = v.z * sc.z + sh.z; v.z = v.z >= 0.f ? v.z : LEAK * v.z;
        v.w = v.w * sc.w + sh.w; v.w = v.w >= 0.f ? v.w : LEAK * v.w;
        o4[i] = v;
    }
}

// ---------------------------------------------------------------------------
extern "C" void kernel_launch(void* const* d_in, const int* in_sizes, int n_in,
                              void* d_out, int out_size, void* d_ws, size_t ws_size,
                              hipStream_t stream)
{
    const float* feats  = (const float*)d_in[0];
    const float* W      = (const float*)d_in[1];
    const float* gamma  = (const float*)d_in[2];
    const float* beta   = (const float*)d_in[3];
    const int*  in_idx  = (const int*)d_in[4];
    const int*  out_idx = (const int*)d_in[5];

    const int P     = in_sizes[4] / KOFF;     // 262144
    const int n_out = out_size / C_OUT;       // 262144

    dim3 grid_g(P / TILE_P, KOFF);            // 2048 x 4

    const size_t half_bytes = (size_t)n_out * C_OUT * sizeof(__half);   // 67 MB
    const size_t wt_off     = (half_bytes + 1024 + 255) & ~(size_t)255;
    const size_t wt_bytes   = (size_t)KOFF * C_OUT * C_IN * sizeof(unsigned short); // 64 KB

    if (ws_size >= wt_off + wt_bytes) {
        __half2* outh = (__half2*)d_ws;
        float* stats = (float*)((char*)d_ws + half_bytes);
        unsigned short* Wt = (unsigned short*)((char*)d_ws + wt_off);

        // One memset covers accumulator + stats (stats sits right after).
        hipMemsetAsync(d_ws, 0, half_bytes + 2 * C_OUT * sizeof(float), stream);

        build_wt_kernel<<<KOFF, 256, 0, stream>>>(W, Wt);
        scatter_gemm_mfma_kernel<<<grid_g, 256, 0, stream>>>(feats, Wt, in_idx, out_idx, outh, P);
        bn_stats_half_kernel<<<1024, 256, 0, stream>>>(outh, stats, n_out);
        bn_apply_half_kernel<<<2048, 256, 0, stream>>>(outh, (float*)d_out, stats,
                                                       gamma, beta, n_out, 1.0f / n_out);
    } else {
        float* out   = (float*)d_out;
        float* stats = (float*)d_ws;
        hipMemsetAsync(d_out, 0, (size_t)out_size * sizeof(float), stream);
        hipMemsetAsync(d_ws, 0, 2 * C_OUT * sizeof(float), stream);

        scatter_gemm_f32_kernel<<<grid_g, 256, 0, stream>>>(feats, W, in_idx, out_idx, out, P);
        bn_stats_f32_kernel<<<1024, 256, 0, stream>>>(out, stats, n_out);
        bn_apply_f32_kernel<<<2048, 256, 0, stream>>>(out, stats, gamma, beta, n_out, 1.0f / n_out);
    }
}

// Round 3
// 607.619 us; speedup vs baseline: 1.4933x; 1.1513x over previous
//
#include <hip/hip_runtime.h>
#include <hip/hip_fp16.h>

// SparseConvolutionDownsample: rulebook sparse conv (gather -> GEMM -> scatter-add)
// + BatchNorm over active sites + LeakyReLU(0.333).
//
// Constants: C_IN=64, C_OUT=128, K=4, P=262144, n_out=262144.
//
// R6: two-stage BN stats. Bookkeeping across R3/R4/R5 shows aux (total - k1)
// constant at ~454us vs a ~55us HBM floor. Suspect: bn_stats' final
// atomicAdds -> 1024-deep same-address serial chains (256 addrs, ~175ns/op
// ~ 180us). Stage 1 now stores per-block partials (no atomics); stage 2
// reduces 2048 partials with atomic depth 8. k1 itself is at the ~274 Gops/s
// pk-f16 atomic ceiling (245us) and is left untouched this round.
// Fallbacks: R5 atomic-stats path if ws too small for partials; R2 fp32 path
// if ws tiny.

#define C_IN   64
#define C_OUT  128
#define KOFF   4
#define TILE_P 128
#define SF_LD  72            // bf16 elems/row: 144B stride (16B-aligned)
#define BN_EPS 1e-4f
#define LEAK   0.333f
#define STATS_BLOCKS 2048    // stage-1 grid for partial stats

typedef __attribute__((ext_vector_type(8)))  short short8;
typedef __attribute__((ext_vector_type(4)))  float f32x4;
typedef __attribute__((ext_vector_type(16))) float f32x16;

__device__ inline unsigned short f32_to_bf16_rn(float x) {
    unsigned int b = __float_as_uint(x);
    unsigned int r = (b + 0x7FFFu + ((b >> 16) & 1u)) >> 16;
    return (unsigned short)r;
}

struct h2pair { __half2 a, b; };   // 8 B = 4 channels

// ===========================================================================
// Pre-kernel: W [K][C_IN][C_OUT] fp32 -> Wt [K][C_OUT][C_IN] bf16 (64 KB).
// ===========================================================================
__global__ __launch_bounds__(256) void build_wt_kernel(
    const float* __restrict__ W, unsigned short* __restrict__ Wt)
{
    const int k = blockIdx.x;          // 0..3
    const int t = threadIdx.x;         // 256
    const int n  = t >> 1;             // output channel 0..127
    const int c0 = (t & 1) * 32;       // input-channel half

    unsigned int buf[16];
    #pragma unroll
    for (int j = 0; j < 16; ++j) {
        int c = c0 + 2 * j;
        unsigned short lo = f32_to_bf16_rn(W[((size_t)k * C_IN + c) * C_OUT + n]);
        unsigned short hi = f32_to_bf16_rn(W[((size_t)k * C_IN + c + 1) * C_OUT + n]);
        buf[j] = (unsigned int)lo | ((unsigned int)hi << 16);
    }
    uint4* dst = (uint4*)(Wt + ((size_t)k * C_OUT + n) * C_IN + c0);
    dst[0] = make_uint4(buf[0],  buf[1],  buf[2],  buf[3]);
    dst[1] = make_uint4(buf[4],  buf[5],  buf[6],  buf[7]);
    dst[2] = make_uint4(buf[8],  buf[9],  buf[10], buf[11]);
    dst[3] = make_uint4(buf[12], buf[13], buf[14], buf[15]);
}

// ===========================================================================
// Kernel 1h: gather + 32x32x16 MFMA + full-segment pk_add_f16 scatter.
// 4 waves/block; wave w owns cols 32w..32w+31. D layout: col = lane&31,
// row = (reg&3) + 8*(reg>>2) + 4*(lane>>5). At the 274 Gops/s atomic ceiling.
// ===========================================================================
__global__ __launch_bounds__(256) void scatter_gemm_mfma_kernel(
    const float* __restrict__ feats, const unsigned short* __restrict__ Wt,
    const int* __restrict__ in_idx, const int* __restrict__ out_idx,
    __half2* __restrict__ outh, int P)
{
    __shared__ unsigned short sF[TILE_P][SF_LD];   // 18.4 KB bf16 feats tile
    __shared__ int sO[TILE_P];                     // out rows for this tile

    const int tid = threadIdx.x;
    const int k  = blockIdx.y;
    const int p0 = blockIdx.x * TILE_P;

    if (tid < TILE_P)
        sO[tid] = out_idx[(size_t)k * P + p0 + tid];

    for (int i = tid; i < TILE_P * (C_IN / 4); i += 256) {
        int r  = i >> 4;
        int c4 = i & 15;
        int src = in_idx[(size_t)k * P + p0 + r];
        float4 v = ((const float4*)(feats + (size_t)src * C_IN))[c4];
        unsigned int lo = (unsigned int)f32_to_bf16_rn(v.x) | ((unsigned int)f32_to_bf16_rn(v.y) << 16);
        unsigned int hi = (unsigned int)f32_to_bf16_rn(v.z) | ((unsigned int)f32_to_bf16_rn(v.w) << 16);
        *(uint2*)&sF[r][c4 * 4] = make_uint2(lo, hi);
    }

    const int l  = tid & 63;
    const int w  = tid >> 6;        // wave id -> col base 32w
    const int c  = l & 31;          // A row / B col / D col
    const int hi = l >> 5;          // k-half selector; D row +4*hi
    const bool odd = (c & 1) != 0;
    const int cpair = 16 * w + (c >> 1);   // __half2 index of this lane's col pair

    short8 bfr[4];
    {
        const unsigned short* wb = Wt + ((size_t)(k * C_OUT + 32 * w + c)) * C_IN + 8 * hi;
        #pragma unroll
        for (int s = 0; s < 4; ++s)
            bfr[s] = *(const short8*)(wb + 16 * s);
    }

    __syncthreads();

    #pragma unroll
    for (int m = 0; m < 4; ++m) {
        f32x16 acc;
        #pragma unroll
        for (int j = 0; j < 16; ++j) acc[j] = 0.f;

        #pragma unroll
        for (int s = 0; s < 4; ++s) {
            short8 a = *(const short8*)&sF[32 * m + c][16 * s + 8 * hi];
            acc = __builtin_amdgcn_mfma_f32_32x32x16_bf16(a, bfr[s], acc, 0, 0, 0);
        }

        // Pair regs (e,e+1) -> rows (R,R+1); shfl_xor(1) pairs adjacent-lane
        // cols. Per atomic instr: 4 distinct rows, each a full 64B segment.
        #pragma unroll
        for (int e = 0; e < 16; e += 2) {
            const int rbase = 32 * m + (e & 3) + 8 * (e >> 2) + 4 * hi;
            float va = acc[e], vb = acc[e + 1];
            float ta = __shfl_xor(va, 1);
            float tb = __shfl_xor(vb, 1);
            int row = sO[rbase + (odd ? 1 : 0)];
            __half2 h = odd ? __floats2half2_rn(tb, vb) : __floats2half2_rn(va, ta);
            unsafeAtomicAdd(outh + (size_t)row * (C_OUT / 2) + cpair, h);
        }
    }
}

// ===========================================================================
// Kernel 2h stage 1: per-block partial sum/sumsq -> partial[b][0:128]=sum,
// partial[b][128:256]=sumsq. Plain stores, no atomics.
// ===========================================================================
__global__ __launch_bounds__(256) void bn_stats_partial_kernel(
    const __half2* __restrict__ outh, float* __restrict__ partial, int n_out)
{
    const int tid = threadIdx.x;
    const int c4   = tid & 31;   // channels 4*c4 .. 4*c4+3
    const int rgrp = tid >> 5;   // 8 rows per block-iteration

    float4 s  = make_float4(0.f, 0.f, 0.f, 0.f);
    float4 s2 = make_float4(0.f, 0.f, 0.f, 0.f);
    for (int r = blockIdx.x * 8 + rgrp; r < n_out; r += gridDim.x * 8) {
        h2pair u = ((const h2pair*)(outh + (size_t)r * (C_OUT / 2)))[c4];
        float2 fa = __half22float2(u.a), fb = __half22float2(u.b);
        s.x += fa.x; s.y += fa.y; s.z += fb.x; s.w += fb.y;
        s2.x += fa.x * fa.x; s2.y += fa.y * fa.y; s2.z += fb.x * fb.x; s2.w += fb.y * fb.y;
    }

    __shared__ float4 red[256], red2[256];
    red[tid] = s; red2[tid] = s2;
    __syncthreads();
    if (tid < 32) {
        #pragma unroll
        for (int j = 1; j < 8; ++j) {
            float4 a = red[tid + 32 * j], b = red2[tid + 32 * j];
            s.x += a.x; s.y += a.y; s.z += a.z; s.w += a.w;
            s2.x += b.x; s2.y += b.y; s2.z += b.z; s2.w += b.w;
        }
        float* pb = partial + (size_t)blockIdx.x * 2 * C_OUT;
        ((float4*)pb)[tid] = s;                 // sums: pb[4tid..4tid+3]
        ((float4*)(pb + C_OUT))[tid] = s2;      // sumsq
    }
}

// Stage 2: reduce partials (atomic depth = gridDim.x = 8 per address).
__global__ __launch_bounds__(256) void bn_reduce_kernel(
    const float* __restrict__ partial, float* __restrict__ stats)
{
    const int tid = threadIdx.x;          // stat slot 0..255
    const int b0 = blockIdx.x * (STATS_BLOCKS / 8);
    float a = 0.f;
    for (int b = b0; b < b0 + STATS_BLOCKS / 8; ++b)
        a += partial[(size_t)b * 2 * C_OUT + tid];
    atomicAdd(&stats[tid], a);
}

// Kernel 2h (fallback, atomic stats): used when ws lacks partial space.
__global__ __launch_bounds__(256) void bn_stats_half_kernel(
    const __half2* __restrict__ outh, float* __restrict__ stats, int n_out)
{
    const int tid = threadIdx.x;
    const int c4   = tid & 31;
    const int rgrp = tid >> 5;

    float4 s  = make_float4(0.f, 0.f, 0.f, 0.f);
    float4 s2 = make_float4(0.f, 0.f, 0.f, 0.f);
    for (int r = blockIdx.x * 8 + rgrp; r < n_out; r += gridDim.x * 8) {
        h2pair u = ((const h2pair*)(outh + (size_t)r * (C_OUT / 2)))[c4];
        float2 fa = __half22float2(u.a), fb = __half22float2(u.b);
        s.x += fa.x; s.y += fa.y; s.z += fb.x; s.w += fb.y;
        s2.x += fa.x * fa.x; s2.y += fa.y * fa.y; s2.z += fb.x * fb.x; s2.w += fb.y * fb.y;
    }

    __shared__ float4 red[256], red2[256];
    red[tid] = s; red2[tid] = s2;
    __syncthreads();
    if (tid < 32) {
        #pragma unroll
        for (int j = 1; j < 8; ++j) {
            float4 a = red[tid + 32 * j], b = red2[tid + 32 * j];
            s.x += a.x; s.y += a.y; s.z += a.z; s.w += a.w;
            s2.x += b.x; s2.y += b.y; s2.z += b.z; s2.w += b.w;
        }
        atomicAdd(&stats[4 * tid + 0], s.x);
        atomicAdd(&stats[4 * tid + 1], s.y);
        atomicAdd(&stats[4 * tid + 2], s.z);
        atomicAdd(&stats[4 * tid + 3], s.w);
        atomicAdd(&stats[C_OUT + 4 * tid + 0], s2.x);
        atomicAdd(&stats[C_OUT + 4 * tid + 1], s2.y);
        atomicAdd(&stats[C_OUT + 4 * tid + 2], s2.z);
        atomicAdd(&stats[C_OUT + 4 * tid + 3], s2.w);
    }
}

// Kernel 3h: normalize + LeakyReLU, half in -> fp32 out.
__global__ __launch_bounds__(256) void bn_apply_half_kernel(
    const __half2* __restrict__ outh, float* __restrict__ out,
    const float* __restrict__ stats,
    const float* __restrict__ gamma, const float* __restrict__ beta,
    int n_out, float inv_n)
{
    const size_t total = (size_t)n_out * (C_OUT / 4);   // h2pair units
    size_t i = (size_t)blockIdx.x * 256 + threadIdx.x;
    const int c = (int)(i & 31) * 4;

    float4 sc, sh;
    {
        float m0 = stats[c + 0] * inv_n, m1 = stats[c + 1] * inv_n,
              m2 = stats[c + 2] * inv_n, m3 = stats[c + 3] * inv_n;
        float v0 = stats[C_OUT + c + 0] * inv_n - m0 * m0;
        float v1 = stats[C_OUT + c + 1] * inv_n - m1 * m1;
        float v2 = stats[C_OUT + c + 2] * inv_n - m2 * m2;
        float v3 = stats[C_OUT + c + 3] * inv_n - m3 * m3;
        sc.x = gamma[c + 0] * rsqrtf(v0 + BN_EPS);
        sc.y = gamma[c + 1] * rsqrtf(v1 + BN_EPS);
        sc.z = gamma[c + 2] * rsqrtf(v2 + BN_EPS);
        sc.w = gamma[c + 3] * rsqrtf(v3 + BN_EPS);
        sh.x = beta[c + 0] - m0 * sc.x;
        sh.y = beta[c + 1] - m1 * sc.y;
        sh.z = beta[c + 2] - m2 * sc.z;
        sh.w = beta[c + 3] - m3 * sc.w;
    }

    const h2pair* ih = (const h2pair*)outh;
    float4* o4 = (float4*)out;
    for (; i < total; i += (size_t)gridDim.x * 256) {
        h2pair u = ih[i];
        float2 fa = __half22float2(u.a), fb = __half22float2(u.b);
        float4 v = make_float4(fa.x, fa.y, fb.x, fb.y);
        v.x = v.x * sc.x + sh.x; v.x = v.x >= 0.f ? v.x : LEAK * v.x;
        v.y = v.y * sc.y + sh.y; v.y = v.y >= 0.f ? v.y : LEAK * v.y;
        v.z = v.z * sc.z + sh.z; v.z = v.z >= 0.f ? v.z : LEAK * v.z;
        v.w = v.w * sc.w + sh.w; v.w = v.w >= 0.f ? v.w : LEAK * v.w;
        o4[i] = v;
    }
}

// ===========================================================================
// FP32 FALLBACK PATH (R2, unchanged) — used if ws_size too small
// ===========================================================================

__global__ __launch_bounds__(256) void scatter_gemm_f32_kernel(
    const float* __restrict__ feats, const float* __restrict__ W,
    const int* __restrict__ in_idx, const int* __restrict__ out_idx,
    float* __restrict__ out, int P)
{
    __shared__ float sW[C_IN][C_OUT];
    __shared__ unsigned short sF[TILE_P][66];

    const int tid = threadIdx.x;
    const int k  = blockIdx.y;
    const int p0 = blockIdx.x * TILE_P;

    const float4* Wk4 = (const float4*)(W + (size_t)k * C_IN * C_OUT);
    float4* sW4 = (float4*)&sW[0][0];
    #pragma unroll
    for (int i = tid; i < C_IN * C_OUT / 4; i += 256)
        sW4[i] = Wk4[i];

    for (int i = tid; i < TILE_P * (C_IN / 4); i += 256) {
        int r  = i >> 4;
        int c4 = i & 15;
        int src = in_idx[(size_t)k * P + p0 + r];
        float4 v = ((const float4*)(feats + (size_t)src * C_IN))[c4];
        unsigned int lo = (unsigned int)f32_to_bf16_rn(v.x) | ((unsigned int)f32_to_bf16_rn(v.y) << 16);
        unsigned int hi = (unsigned int)f32_to_bf16_rn(v.z) | ((unsigned int)f32_to_bf16_rn(v.w) << 16);
        unsigned int* dst = (unsigned int*)&sF[r][c4 * 4];
        dst[0] = lo;
        dst[1] = hi;
    }
    __syncthreads();

    const int tx = tid & 15;
    const int ty = tid >> 4;

    float acc[8][8];
    #pragma unroll
    for (int r = 0; r < 8; ++r)
        #pragma unroll
        for (int j = 0; j < 8; ++j) acc[r][j] = 0.f;

    #pragma unroll 4
    for (int kk2 = 0; kk2 < C_IN / 2; ++kk2) {
        float w0[8], w1[8];
        #pragma unroll
        for (int j = 0; j < 8; ++j) {
            w0[j] = sW[2 * kk2 + 0][tx + 16 * j];
            w1[j] = sW[2 * kk2 + 1][tx + 16 * j];
        }
        float f0[8], f1[8];
        #pragma unroll
        for (int r = 0; r < 8; ++r) {
            unsigned int u = *(const unsigned int*)&sF[8 * ty + r][2 * kk2];
            f0[r] = __uint_as_float(u << 16);
            f1[r] = __uint_as_float(u & 0xFFFF0000u);
        }
        #pragma unroll
        for (int r = 0; r < 8; ++r)
            #pragma unroll
            for (int j = 0; j < 8; ++j) {
                acc[r][j] = fmaf(f0[r], w0[j], acc[r][j]);
                acc[r][j] = fmaf(f1[r], w1[j], acc[r][j]);
            }
    }

    #pragma unroll
    for (int r = 0; r < 8; ++r) {
        int orow = out_idx[(size_t)k * P + p0 + 8 * ty + r];
        float* op = out + (size_t)orow * C_OUT + tx;
        #pragma unroll
        for (int j = 0; j < 8; ++j)
            atomicAdd(op + 16 * j, acc[r][j]);
    }
}

__global__ __launch_bounds__(256) void bn_stats_f32_kernel(
    const float* __restrict__ out, float* __restrict__ stats, int n_out)
{
    const int tid = threadIdx.x;
    const int c4   = tid & 31;
    const int rgrp = tid >> 5;

    float4 s  = make_float4(0.f, 0.f, 0.f, 0.f);
    float4 s2 = make_float4(0.f, 0.f, 0.f, 0.f);
    for (int r = blockIdx.x * 8 + rgrp; r < n_out; r += gridDim.x * 8) {
        float4 v = ((const float4*)(out + (size_t)r * C_OUT))[c4];
        s.x += v.x; s.y += v.y; s.z += v.z; s.w += v.w;
        s2.x += v.x * v.x; s2.y += v.y * v.y; s2.z += v.z * v.z; s2.w += v.w * v.w;
    }

    __shared__ float4 red[256], red2[256];
    red[tid] = s; red2[tid] = s2;
    __syncthreads();
    if (tid < 32) {
        #pragma unroll
        for (int j = 1; j < 8; ++j) {
            float4 a = red[tid + 32 * j], b = red2[tid + 32 * j];
            s.x += a.x; s.y += a.y; s.z += a.z; s.w += a.w;
            s2.x += b.x; s2.y += b.y; s2.z += b.z; s2.w += b.w;
        }
        atomicAdd(&stats[4 * tid + 0], s.x);
        atomicAdd(&stats[4 * tid + 1], s.y);
        atomicAdd(&stats[4 * tid + 2], s.z);
        atomicAdd(&stats[4 * tid + 3], s.w);
        atomicAdd(&stats[C_OUT + 4 * tid + 0], s2.x);
        atomicAdd(&stats[C_OUT + 4 * tid + 1], s2.y);
        atomicAdd(&stats[C_OUT + 4 * tid + 2], s2.z);
        atomicAdd(&stats[C_OUT + 4 * tid + 3], s2.w);
    }
}

__global__ __launch_bounds__(256) void bn_apply_f32_kernel(
    float* __restrict__ out, const float* __restrict__ stats,
    const float* __restrict__ gamma, const float* __restrict__ beta,
    int n_out, float inv_n)
{
    const size_t total = (size_t)n_out * (C_OUT / 4);
    size_t i = (size_t)blockIdx.x * 256 + threadIdx.x;
    const int c = (int)(i & 31) * 4;

    float4 sc, sh;
    {
        float m0 = stats[c + 0] * inv_n, m1 = stats[c + 1] * inv_n,
              m2 = stats[c + 2] * inv_n, m3 = stats[c + 3] * inv_n;
        float v0 = stats[C_OUT + c + 0] * inv_n - m0 * m0;
        float v1 = stats[C_OUT + c + 1] * inv_n - m1 * m1;
        float v2 = stats[C_OUT + c + 2] * inv_n - m2 * m2;
        float v3 = stats[C_OUT + c + 3] * inv_n - m3 * m3;
        sc.x = gamma[c + 0] * rsqrtf(v0 + BN_EPS);
        sc.y = gamma[c + 1] * rsqrtf(v1 + BN_EPS);
        sc.z = gamma[c + 2] * rsqrtf(v2 + BN_EPS);
        sc.w = gamma[c + 3] * rsqrtf(v3 + BN_EPS);
        sh.x = beta[c + 0] - m0 * sc.x;
        sh.y = beta[c + 1] - m1 * sc.y;
        sh.z = beta[c + 2] - m2 * sc.z;
        sh.w = beta[c + 3] - m3 * sc.w;
    }

    float4* o4 = (float4*)out;
    for (; i < total; i += (size_t)gridDim.x * 256) {
        float4 v = o4[i];
        v.x = v.x * sc.x + sh.x; v.x = v.x >= 0.f ? v.x : LEAK * v.x;
        v.y = v.y * sc.y + sh.y; v.y = v.y >= 0.f ? v.y : LEAK * v.y;
        v.z = v.z * sc.z + sh.z; v.z = v.z >= 0.f ? v.z : LEAK * v.z;
        v.w = v.w * sc.w + sh.w; v.w = v.w >= 0.f ? v.w : LEAK * v.w;
        o4[i] = v;
    }
}

// ---------------------------------------------------------------------------
extern "C" void kernel_launch(void* const* d_in, const int* in_sizes, int n_in,
                              void* d_out, int out_size, void* d_ws, size_t ws_size,
                              hipStream_t stream)
{
    const float* feats  = (const float*)d_in[0];
    const float* W      = (const float*)d_in[1];
    const float* gamma  = (const float*)d_in[2];
    const float* beta   = (const float*)d_in[3];
    const int*  in_idx  = (const int*)d_in[4];
    const int*  out_idx = (const int*)d_in[5];

    const int P     = in_sizes[4] / KOFF;     // 262144
    const int n_out = out_size / C_OUT;       // 262144

    dim3 grid_g(P / TILE_P, KOFF);            // 2048 x 4

    const size_t half_bytes    = (size_t)n_out * C_OUT * sizeof(__half);   // 67 MB
    const size_t wt_off        = (half_bytes + 1024 + 255) & ~(size_t)255;
    const size_t wt_bytes      = (size_t)KOFF * C_OUT * C_IN * sizeof(unsigned short); // 64 KB
    const size_t partial_off   = wt_off + ((wt_bytes + 255) & ~(size_t)255);
    const size_t partial_bytes = (size_t)STATS_BLOCKS * 2 * C_OUT * sizeof(float);     // 2 MB

    if (ws_size >= partial_off + partial_bytes) {
        __half2* outh = (__half2*)d_ws;
        float* stats = (float*)((char*)d_ws + half_bytes);
        unsigned short* Wt = (unsigned short*)((char*)d_ws + wt_off);
        float* partial = (float*)((char*)d_ws + partial_off);

        // One memset covers accumulator + stats (stats sits right after).
        hipMemsetAsync(d_ws, 0, half_bytes + 2 * C_OUT * sizeof(float), stream);

        build_wt_kernel<<<KOFF, 256, 0, stream>>>(W, Wt);
        scatter_gemm_mfma_kernel<<<grid_g, 256, 0, stream>>>(feats, Wt, in_idx, out_idx, outh, P);
        bn_stats_partial_kernel<<<STATS_BLOCKS, 256, 0, stream>>>(outh, partial, n_out);
        bn_reduce_kernel<<<8, 256, 0, stream>>>(partial, stats);
        bn_apply_half_kernel<<<2048, 256, 0, stream>>>(outh, (float*)d_out, stats,
                                                       gamma, beta, n_out, 1.0f / n_out);
    } else if (ws_size >= wt_off + wt_bytes) {
        __half2* outh = (__half2*)d_ws;
        float* stats = (float*)((char*)d_ws + half_bytes);
        unsigned short* Wt = (unsigned short*)((char*)d_ws + wt_off);

        hipMemsetAsync(d_ws, 0, half_bytes + 2 * C_OUT * sizeof(float), stream);

        build_wt_kernel<<<KOFF, 256, 0, stream>>>(W, Wt);
        scatter_gemm_mfma_kernel<<<grid_g, 256, 0, stream>>>(feats, Wt, in_idx, out_idx, outh, P);
        bn_stats_half_kernel<<<1024, 256, 0, stream>>>(outh, stats, n_out);
        bn_apply_half_kernel<<<2048, 256, 0, stream>>>(outh, (float*)d_out, stats,
                                                       gamma, beta, n_out, 1.0f / n_out);
    } else {
        float* out   = (float*)d_out;
        float* stats = (float*)d_ws;
        hipMemsetAsync(d_out, 0, (size_t)out_size * sizeof(float), stream);
        hipMemsetAsync(d_ws, 0, 2 * C_OUT * sizeof(float), stream);

        scatter_gemm_f32_kernel<<<grid_g, 256, 0, stream>>>(feats, W, in_idx, out_idx, out, P);
        bn_stats_f32_kernel<<<1024, 256, 0, stream>>>(out, stats, n_out);
        bn_apply_f32_kernel<<<2048, 256, 0, stream>>>(out, stats, gamma, beta, n_out, 1.0f / n_out);
    }
}

// Round 4
// 607.268 us; speedup vs baseline: 1.4941x; 1.0006x over previous
//
#include <hip/hip_runtime.h>
#include <hip/hip_fp16.h>

// SparseConvolutionDownsample: rulebook sparse conv (gather -> GEMM -> scatter-add)
// + BatchNorm over active sites + LeakyReLU(0.333).
//
// Constants: C_IN=64, C_OUT=128, K=4, P=262144, n_out=262144.
//
// R7: replace hipMemsetAsync(67 MB) with a compute-kernel zero fill, fused
// with the W->bf16 transpose (extra blocks). Theory: large stream memsets go
// through the SDMA/blit path at far below HBM write BW; the ~250us of aux
// time unexplained by traffic matches a ~0.3-0.7 TB/s constant-fill. k1 is at
// the ~274 Gops/s pk-f16 atomic ceiling (245us) and is left untouched.
// Fallbacks: R6 memset+atomic-stats path if ws too small for partials; R2
// fp32 path if ws tiny.

#define C_IN   64
#define C_OUT  128
#define KOFF   4
#define TILE_P 128
#define SF_LD  72            // bf16 elems/row: 144B stride (16B-aligned)
#define BN_EPS 1e-4f
#define LEAK   0.333f
#define STATS_BLOCKS 2048    // stage-1 grid for partial stats
#define FILL_BLOCKS  4096    // zero-fill grid (plus KOFF wt blocks)

typedef __attribute__((ext_vector_type(8)))  short short8;
typedef __attribute__((ext_vector_type(4)))  float f32x4;
typedef __attribute__((ext_vector_type(16))) float f32x16;

__device__ inline unsigned short f32_to_bf16_rn(float x) {
    unsigned int b = __float_as_uint(x);
    unsigned int r = (b + 0x7FFFu + ((b >> 16) & 1u)) >> 16;
    return (unsigned short)r;
}

struct h2pair { __half2 a, b; };   // 8 B = 4 channels

// ===========================================================================
// Fused pre-kernel: blocks [0,FILL_BLOCKS) zero the accumulator+stats region
// with dwordx4 stores; blocks [FILL_BLOCKS, FILL_BLOCKS+KOFF) transpose
// W [K][C_IN][C_OUT] fp32 -> Wt [K][C_OUT][C_IN] bf16 (64 KB).
// ===========================================================================
__global__ __launch_bounds__(256) void fill_wt_kernel(
    const float* __restrict__ W, unsigned short* __restrict__ Wt,
    uint4* __restrict__ fill, size_t fill_u4)
{
    const int bid = blockIdx.x;
    if (bid < FILL_BLOCKS) {
        const uint4 z = make_uint4(0u, 0u, 0u, 0u);
        size_t i = (size_t)bid * 256 + threadIdx.x;
        const size_t stride = (size_t)FILL_BLOCKS * 256;
        for (; i < fill_u4; i += stride)
            fill[i] = z;
        return;
    }

    const int k = bid - FILL_BLOCKS;   // 0..KOFF-1
    const int t = threadIdx.x;         // 256
    const int n  = t >> 1;             // output channel 0..127
    const int c0 = (t & 1) * 32;       // input-channel half

    unsigned int buf[16];
    #pragma unroll
    for (int j = 0; j < 16; ++j) {
        int c = c0 + 2 * j;
        unsigned short lo = f32_to_bf16_rn(W[((size_t)k * C_IN + c) * C_OUT + n]);
        unsigned short hi = f32_to_bf16_rn(W[((size_t)k * C_IN + c + 1) * C_OUT + n]);
        buf[j] = (unsigned int)lo | ((unsigned int)hi << 16);
    }
    uint4* dst = (uint4*)(Wt + ((size_t)k * C_OUT + n) * C_IN + c0);
    dst[0] = make_uint4(buf[0],  buf[1],  buf[2],  buf[3]);
    dst[1] = make_uint4(buf[4],  buf[5],  buf[6],  buf[7]);
    dst[2] = make_uint4(buf[8],  buf[9],  buf[10], buf[11]);
    dst[3] = make_uint4(buf[12], buf[13], buf[14], buf[15]);
}

// Standalone Wt build (fallback path only).
__global__ __launch_bounds__(256) void build_wt_kernel(
    const float* __restrict__ W, unsigned short* __restrict__ Wt)
{
    const int k = blockIdx.x;
    const int t = threadIdx.x;
    const int n  = t >> 1;
    const int c0 = (t & 1) * 32;

    unsigned int buf[16];
    #pragma unroll
    for (int j = 0; j < 16; ++j) {
        int c = c0 + 2 * j;
        unsigned short lo = f32_to_bf16_rn(W[((size_t)k * C_IN + c) * C_OUT + n]);
        unsigned short hi = f32_to_bf16_rn(W[((size_t)k * C_IN + c + 1) * C_OUT + n]);
        buf[j] = (unsigned int)lo | ((unsigned int)hi << 16);
    }
    uint4* dst = (uint4*)(Wt + ((size_t)k * C_OUT + n) * C_IN + c0);
    dst[0] = make_uint4(buf[0],  buf[1],  buf[2],  buf[3]);
    dst[1] = make_uint4(buf[4],  buf[5],  buf[6],  buf[7]);
    dst[2] = make_uint4(buf[8],  buf[9],  buf[10], buf[11]);
    dst[3] = make_uint4(buf[12], buf[13], buf[14], buf[15]);
}

// ===========================================================================
// Kernel 1h: gather + 32x32x16 MFMA + full-segment pk_add_f16 scatter.
// 4 waves/block; wave w owns cols 32w..32w+31. D layout: col = lane&31,
// row = (reg&3) + 8*(reg>>2) + 4*(lane>>5). At the 274 Gops/s atomic ceiling.
// ===========================================================================
__global__ __launch_bounds__(256) void scatter_gemm_mfma_kernel(
    const float* __restrict__ feats, const unsigned short* __restrict__ Wt,
    const int* __restrict__ in_idx, const int* __restrict__ out_idx,
    __half2* __restrict__ outh, int P)
{
    __shared__ unsigned short sF[TILE_P][SF_LD];   // 18.4 KB bf16 feats tile
    __shared__ int sO[TILE_P];                     // out rows for this tile

    const int tid = threadIdx.x;
    const int k  = blockIdx.y;
    const int p0 = blockIdx.x * TILE_P;

    if (tid < TILE_P)
        sO[tid] = out_idx[(size_t)k * P + p0 + tid];

    for (int i = tid; i < TILE_P * (C_IN / 4); i += 256) {
        int r  = i >> 4;
        int c4 = i & 15;
        int src = in_idx[(size_t)k * P + p0 + r];
        float4 v = ((const float4*)(feats + (size_t)src * C_IN))[c4];
        unsigned int lo = (unsigned int)f32_to_bf16_rn(v.x) | ((unsigned int)f32_to_bf16_rn(v.y) << 16);
        unsigned int hi = (unsigned int)f32_to_bf16_rn(v.z) | ((unsigned int)f32_to_bf16_rn(v.w) << 16);
        *(uint2*)&sF[r][c4 * 4] = make_uint2(lo, hi);
    }

    const int l  = tid & 63;
    const int w  = tid >> 6;        // wave id -> col base 32w
    const int c  = l & 31;          // A row / B col / D col
    const int hi = l >> 5;          // k-half selector; D row +4*hi
    const bool odd = (c & 1) != 0;
    const int cpair = 16 * w + (c >> 1);   // __half2 index of this lane's col pair

    short8 bfr[4];
    {
        const unsigned short* wb = Wt + ((size_t)(k * C_OUT + 32 * w + c)) * C_IN + 8 * hi;
        #pragma unroll
        for (int s = 0; s < 4; ++s)
            bfr[s] = *(const short8*)(wb + 16 * s);
    }

    __syncthreads();

    #pragma unroll
    for (int m = 0; m < 4; ++m) {
        f32x16 acc;
        #pragma unroll
        for (int j = 0; j < 16; ++j) acc[j] = 0.f;

        #pragma unroll
        for (int s = 0; s < 4; ++s) {
            short8 a = *(const short8*)&sF[32 * m + c][16 * s + 8 * hi];
            acc = __builtin_amdgcn_mfma_f32_32x32x16_bf16(a, bfr[s], acc, 0, 0, 0);
        }

        // Pair regs (e,e+1) -> rows (R,R+1); shfl_xor(1) pairs adjacent-lane
        // cols. Per atomic instr: 4 distinct rows, each a full 64B segment.
        #pragma unroll
        for (int e = 0; e < 16; e += 2) {
            const int rbase = 32 * m + (e & 3) + 8 * (e >> 2) + 4 * hi;
            float va = acc[e], vb = acc[e + 1];
            float ta = __shfl_xor(va, 1);
            float tb = __shfl_xor(vb, 1);
            int row = sO[rbase + (odd ? 1 : 0)];
            __half2 h = odd ? __floats2half2_rn(tb, vb) : __floats2half2_rn(va, ta);
            unsafeAtomicAdd(outh + (size_t)row * (C_OUT / 2) + cpair, h);
        }
    }
}

// ===========================================================================
// Kernel 2h stage 1: per-block partial sum/sumsq -> partial[b][0:128]=sum,
// partial[b][128:256]=sumsq. Plain stores, no atomics.
// ===========================================================================
__global__ __launch_bounds__(256) void bn_stats_partial_kernel(
    const __half2* __restrict__ outh, float* __restrict__ partial, int n_out)
{
    const int tid = threadIdx.x;
    const int c4   = tid & 31;   // channels 4*c4 .. 4*c4+3
    const int rgrp = tid >> 5;   // 8 rows per block-iteration

    float4 s  = make_float4(0.f, 0.f, 0.f, 0.f);
    float4 s2 = make_float4(0.f, 0.f, 0.f, 0.f);
    for (int r = blockIdx.x * 8 + rgrp; r < n_out; r += gridDim.x * 8) {
        h2pair u = ((const h2pair*)(outh + (size_t)r * (C_OUT / 2)))[c4];
        float2 fa = __half22float2(u.a), fb = __half22float2(u.b);
        s.x += fa.x; s.y += fa.y; s.z += fb.x; s.w += fb.y;
        s2.x += fa.x * fa.x; s2.y += fa.y * fa.y; s2.z += fb.x * fb.x; s2.w += fb.y * fb.y;
    }

    __shared__ float4 red[256], red2[256];
    red[tid] = s; red2[tid] = s2;
    __syncthreads();
    if (tid < 32) {
        #pragma unroll
        for (int j = 1; j < 8; ++j) {
            float4 a = red[tid + 32 * j], b = red2[tid + 32 * j];
            s.x += a.x; s.y += a.y; s.z += a.z; s.w += a.w;
            s2.x += b.x; s2.y += b.y; s2.z += b.z; s2.w += b.w;
        }
        float* pb = partial + (size_t)blockIdx.x * 2 * C_OUT;
        ((float4*)pb)[tid] = s;                 // sums: pb[4tid..4tid+3]
        ((float4*)(pb + C_OUT))[tid] = s2;      // sumsq
    }
}

// Stage 2: reduce partials (atomic depth = gridDim.x = 8 per address).
__global__ __launch_bounds__(256) void bn_reduce_kernel(
    const float* __restrict__ partial, float* __restrict__ stats)
{
    const int tid = threadIdx.x;          // stat slot 0..255
    const int b0 = blockIdx.x * (STATS_BLOCKS / 8);
    float a = 0.f;
    for (int b = b0; b < b0 + STATS_BLOCKS / 8; ++b)
        a += partial[(size_t)b * 2 * C_OUT + tid];
    atomicAdd(&stats[tid], a);
}

// Kernel 2h (fallback, atomic stats): used when ws lacks partial space.
__global__ __launch_bounds__(256) void bn_stats_half_kernel(
    const __half2* __restrict__ outh, float* __restrict__ stats, int n_out)
{
    const int tid = threadIdx.x;
    const int c4   = tid & 31;
    const int rgrp = tid >> 5;

    float4 s  = make_float4(0.f, 0.f, 0.f, 0.f);
    float4 s2 = make_float4(0.f, 0.f, 0.f, 0.f);
    for (int r = blockIdx.x * 8 + rgrp; r < n_out; r += gridDim.x * 8) {
        h2pair u = ((const h2pair*)(outh + (size_t)r * (C_OUT / 2)))[c4];
        float2 fa = __half22float2(u.a), fb = __half22float2(u.b);
        s.x += fa.x; s.y += fa.y; s.z += fb.x; s.w += fb.y;
        s2.x += fa.x * fa.x; s2.y += fa.y * fa.y; s2.z += fb.x * fb.x; s2.w += fb.y * fb.y;
    }

    __shared__ float4 red[256], red2[256];
    red[tid] = s; red2[tid] = s2;
    __syncthreads();
    if (tid < 32) {
        #pragma unroll
        for (int j = 1; j < 8; ++j) {
            float4 a = red[tid + 32 * j], b = red2[tid + 32 * j];
            s.x += a.x; s.y += a.y; s.z += a.z; s.w += a.w;
            s2.x += b.x; s2.y += b.y; s2.z += b.z; s2.w += b.w;
        }
        atomicAdd(&stats[4 * tid + 0], s.x);
        atomicAdd(&stats[4 * tid + 1], s.y);
        atomicAdd(&stats[4 * tid + 2], s.z);
        atomicAdd(&stats[4 * tid + 3], s.w);
        atomicAdd(&stats[C_OUT + 4 * tid + 0], s2.x);
        atomicAdd(&stats[C_OUT + 4 * tid + 1], s2.y);
        atomicAdd(&stats[C_OUT + 4 * tid + 2], s2.z);
        atomicAdd(&stats[C_OUT + 4 * tid + 3], s2.w);
    }
}

// Kernel 3h: normalize + LeakyReLU, half in -> fp32 out.
__global__ __launch_bounds__(256) void bn_apply_half_kernel(
    const __half2* __restrict__ outh, float* __restrict__ out,
    const float* __restrict__ stats,
    const float* __restrict__ gamma, const float* __restrict__ beta,
    int n_out, float inv_n)
{
    const size_t total = (size_t)n_out * (C_OUT / 4);   // h2pair units
    size_t i = (size_t)blockIdx.x * 256 + threadIdx.x;
    const int c = (int)(i & 31) * 4;

    float4 sc, sh;
    {
        float m0 = stats[c + 0] * inv_n, m1 = stats[c + 1] * inv_n,
              m2 = stats[c + 2] * inv_n, m3 = stats[c + 3] * inv_n;
        float v0 = stats[C_OUT + c + 0] * inv_n - m0 * m0;
        float v1 = stats[C_OUT + c + 1] * inv_n - m1 * m1;
        float v2 = stats[C_OUT + c + 2] * inv_n - m2 * m2;
        float v3 = stats[C_OUT + c + 3] * inv_n - m3 * m3;
        sc.x = gamma[c + 0] * rsqrtf(v0 + BN_EPS);
        sc.y = gamma[c + 1] * rsqrtf(v1 + BN_EPS);
        sc.z = gamma[c + 2] * rsqrtf(v2 + BN_EPS);
        sc.w = gamma[c + 3] * rsqrtf(v3 + BN_EPS);
        sh.x = beta[c + 0] - m0 * sc.x;
        sh.y = beta[c + 1] - m1 * sc.y;
        sh.z = beta[c + 2] - m2 * sc.z;
        sh.w = beta[c + 3] - m3 * sc.w;
    }

    const h2pair* ih = (const h2pair*)outh;
    float4* o4 = (float4*)out;
    for (; i < total; i += (size_t)gridDim.x * 256) {
        h2pair u = ih[i];
        float2 fa = __half22float2(u.a), fb = __half22float2(u.b);
        float4 v = make_float4(fa.x, fa.y, fb.x, fb.y);
        v.x = v.x * sc.x + sh.x; v.x = v.x >= 0.f ? v.x : LEAK * v.x;
        v.y = v.y * sc.y + sh.y; v.y = v.y >= 0.f ? v.y : LEAK * v.y;
        v.z = v.z * sc.z + sh.z; v.z = v.z >= 0.f ? v.z : LEAK * v.z;
        v.w = v.w * sc.w + sh.w; v.w = v.w >= 0.f ? v.w : LEAK * v.w;
        o4[i] = v;
    }
}

// ===========================================================================
// FP32 FALLBACK PATH (R2, unchanged) — used if ws_size too small
// ===========================================================================

__global__ __launch_bounds__(256) void scatter_gemm_f32_kernel(
    const float* __restrict__ feats, const float* __restrict__ W,
    const int* __restrict__ in_idx, const int* __restrict__ out_idx,
    float* __restrict__ out, int P)
{
    __shared__ float sW[C_IN][C_OUT];
    __shared__ unsigned short sF[TILE_P][66];

    const int tid = threadIdx.x;
    const int k  = blockIdx.y;
    const int p0 = blockIdx.x * TILE_P;

    const float4* Wk4 = (const float4*)(W + (size_t)k * C_IN * C_OUT);
    float4* sW4 = (float4*)&sW[0][0];
    #pragma unroll
    for (int i = tid; i < C_IN * C_OUT / 4; i += 256)
        sW4[i] = Wk4[i];

    for (int i = tid; i < TILE_P * (C_IN / 4); i += 256) {
        int r  = i >> 4;
        int c4 = i & 15;
        int src = in_idx[(size_t)k * P + p0 + r];
        float4 v = ((const float4*)(feats + (size_t)src * C_IN))[c4];
        unsigned int lo = (unsigned int)f32_to_bf16_rn(v.x) | ((unsigned int)f32_to_bf16_rn(v.y) << 16);
        unsigned int hi = (unsigned int)f32_to_bf16_rn(v.z) | ((unsigned int)f32_to_bf16_rn(v.w) << 16);
        unsigned int* dst = (unsigned int*)&sF[r][c4 * 4];
        dst[0] = lo;
        dst[1] = hi;
    }
    __syncthreads();

    const int tx = tid & 15;
    const int ty = tid >> 4;

    float acc[8][8];
    #pragma unroll
    for (int r = 0; r < 8; ++r)
        #pragma unroll
        for (int j = 0; j < 8; ++j) acc[r][j] = 0.f;

    #pragma unroll 4
    for (int kk2 = 0; kk2 < C_IN / 2; ++kk2) {
        float w0[8], w1[8];
        #pragma unroll
        for (int j = 0; j < 8; ++j) {
            w0[j] = sW[2 * kk2 + 0][tx + 16 * j];
            w1[j] = sW[2 * kk2 + 1][tx + 16 * j];
        }
        float f0[8], f1[8];
        #pragma unroll
        for (int r = 0; r < 8; ++r) {
            unsigned int u = *(const unsigned int*)&sF[8 * ty + r][2 * kk2];
            f0[r] = __uint_as_float(u << 16);
            f1[r] = __uint_as_float(u & 0xFFFF0000u);
        }
        #pragma unroll
        for (int r = 0; r < 8; ++r)
            #pragma unroll
            for (int j = 0; j < 8; ++j) {
                acc[r][j] = fmaf(f0[r], w0[j], acc[r][j]);
                acc[r][j] = fmaf(f1[r], w1[j], acc[r][j]);
            }
    }

    #pragma unroll
    for (int r = 0; r < 8; ++r) {
        int orow = out_idx[(size_t)k * P + p0 + 8 * ty + r];
        float* op = out + (size_t)orow * C_OUT + tx;
        #pragma unroll
        for (int j = 0; j < 8; ++j)
            atomicAdd(op + 16 * j, acc[r][j]);
    }
}

__global__ __launch_bounds__(256) void bn_stats_f32_kernel(
    const float* __restrict__ out, float* __restrict__ stats, int n_out)
{
    const int tid = threadIdx.x;
    const int c4   = tid & 31;
    const int rgrp = tid >> 5;

    float4 s  = make_float4(0.f, 0.f, 0.f, 0.f);
    float4 s2 = make_float4(0.f, 0.f, 0.f, 0.f);
    for (int r = blockIdx.x * 8 + rgrp; r < n_out; r += gridDim.x * 8) {
        float4 v = ((const float4*)(out + (size_t)r * C_OUT))[c4];
        s.x += v.x; s.y += v.y; s.z += v.z; s.w += v.w;
        s2.x += v.x * v.x; s2.y += v.y * v.y; s2.z += v.z * v.z; s2.w += v.w * v.w;
    }

    __shared__ float4 red[256], red2[256];
    red[tid] = s; red2[tid] = s2;
    __syncthreads();
    if (tid < 32) {
        #pragma unroll
        for (int j = 1; j < 8; ++j) {
            float4 a = red[tid + 32 * j], b = red2[tid + 32 * j];
            s.x += a.x; s.y += a.y; s.z += a.z; s.w += a.w;
            s2.x += b.x; s2.y += b.y; s2.z += b.z; s2.w += b.w;
        }
        atomicAdd(&stats[4 * tid + 0], s.x);
        atomicAdd(&stats[4 * tid + 1], s.y);
        atomicAdd(&stats[4 * tid + 2], s.z);
        atomicAdd(&stats[4 * tid + 3], s.w);
        atomicAdd(&stats[C_OUT + 4 * tid + 0], s2.x);
        atomicAdd(&stats[C_OUT + 4 * tid + 1], s2.y);
        atomicAdd(&stats[C_OUT + 4 * tid + 2], s2.z);
        atomicAdd(&stats[C_OUT + 4 * tid + 3], s2.w);
    }
}

__global__ __launch_bounds__(256) void bn_apply_f32_kernel(
    float* __restrict__ out, const float* __restrict__ stats,
    const float* __restrict__ gamma, const float* __restrict__ beta,
    int n_out, float inv_n)
{
    const size_t total = (size_t)n_out * (C_OUT / 4);
    size_t i = (size_t)blockIdx.x * 256 + threadIdx.x;
    const int c = (int)(i & 31) * 4;

    float4 sc, sh;
    {
        float m0 = stats[c + 0] * inv_n, m1 = stats[c + 1] * inv_n,
              m2 = stats[c + 2] * inv_n, m3 = stats[c + 3] * inv_n;
        float v0 = stats[C_OUT + c + 0] * inv_n - m0 * m0;
        float v1 = stats[C_OUT + c + 1] * inv_n - m1 * m1;
        float v2 = stats[C_OUT + c + 2] * inv_n - m2 * m2;
        float v3 = stats[C_OUT + c + 3] * inv_n - m3 * m3;
        sc.x = gamma[c + 0] * rsqrtf(v0 + BN_EPS);
        sc.y = gamma[c + 1] * rsqrtf(v1 + BN_EPS);
        sc.z = gamma[c + 2] * rsqrtf(v2 + BN_EPS);
        sc.w = gamma[c + 3] * rsqrtf(v3 + BN_EPS);
        sh.x = beta[c + 0] - m0 * sc.x;
        sh.y = beta[c + 1] - m1 * sc.y;
        sh.z = beta[c + 2] - m2 * sc.z;
        sh.w = beta[c + 3] - m3 * sc.w;
    }

    float4* o4 = (float4*)out;
    for (; i < total; i += (size_t)gridDim.x * 256) {
        float4 v = o4[i];
        v.x = v.x * sc.x + sh.x; v.x = v.x >= 0.f ? v.x : LEAK * v.x;
        v.y = v.y * sc.y + sh.y; v.y = v.y >= 0.f ? v.y : LEAK * v.y;
        v.z = v.z * sc.z + sh.z; v.z = v.z >= 0.f ? v.z : LEAK * v.z;
        v.w = v.w * sc.w + sh.w; v.w = v.w >= 0.f ? v.w : LEAK * v.w;
        o4[i] = v;
    }
}

// ---------------------------------------------------------------------------
extern "C" void kernel_launch(void* const* d_in, const int* in_sizes, int n_in,
                              void* d_out, int out_size, void* d_ws, size_t ws_size,
                              hipStream_t stream)
{
    const float* feats  = (const float*)d_in[0];
    const float* W      = (const float*)d_in[1];
    const float* gamma  = (const float*)d_in[2];
    const float* beta   = (const float*)d_in[3];
    const int*  in_idx  = (const int*)d_in[4];
    const int*  out_idx = (const int*)d_in[5];

    const int P     = in_sizes[4] / KOFF;     // 262144
    const int n_out = out_size / C_OUT;       // 262144

    dim3 grid_g(P / TILE_P, KOFF);            // 2048 x 4

    const size_t half_bytes    = (size_t)n_out * C_OUT * sizeof(__half);   // 67 MB
    const size_t stats_bytes   = 2 * C_OUT * sizeof(float);                // 1 KB
    const size_t wt_off        = (half_bytes + stats_bytes + 255) & ~(size_t)255;
    const size_t wt_bytes      = (size_t)KOFF * C_OUT * C_IN * sizeof(unsigned short); // 64 KB
    const size_t partial_off   = wt_off + ((wt_bytes + 255) & ~(size_t)255);
    const size_t partial_bytes = (size_t)STATS_BLOCKS * 2 * C_OUT * sizeof(float);     // 2 MB

    if (ws_size >= partial_off + partial_bytes) {
        __half2* outh = (__half2*)d_ws;
        float* stats = (float*)((char*)d_ws + half_bytes);
        unsigned short* Wt = (unsigned short*)((char*)d_ws + wt_off);
        float* partial = (float*)((char*)d_ws + partial_off);

        // Zero accumulator + stats with a compute kernel (not SDMA memset);
        // Wt transpose rides along as 4 extra blocks.
        const size_t fill_u4 = (half_bytes + stats_bytes) / 16;
        fill_wt_kernel<<<FILL_BLOCKS + KOFF, 256, 0, stream>>>(W, Wt, (uint4*)d_ws, fill_u4);

        scatter_gemm_mfma_kernel<<<grid_g, 256, 0, stream>>>(feats, Wt, in_idx, out_idx, outh, P);
        bn_stats_partial_kernel<<<STATS_BLOCKS, 256, 0, stream>>>(outh, partial, n_out);
        bn_reduce_kernel<<<8, 256, 0, stream>>>(partial, stats);
        bn_apply_half_kernel<<<2048, 256, 0, stream>>>(outh, (float*)d_out, stats,
                                                       gamma, beta, n_out, 1.0f / n_out);
    } else if (ws_size >= wt_off + wt_bytes) {
        __half2* outh = (__half2*)d_ws;
        float* stats = (float*)((char*)d_ws + half_bytes);
        unsigned short* Wt = (unsigned short*)((char*)d_ws + wt_off);

        hipMemsetAsync(d_ws, 0, half_bytes + stats_bytes, stream);

        build_wt_kernel<<<KOFF, 256, 0, stream>>>(W, Wt);
        scatter_gemm_mfma_kernel<<<grid_g, 256, 0, stream>>>(feats, Wt, in_idx, out_idx, outh, P);
        bn_stats_half_kernel<<<1024, 256, 0, stream>>>(outh, stats, n_out);
        bn_apply_half_kernel<<<2048, 256, 0, stream>>>(outh, (float*)d_out, stats,
                                                       gamma, beta, n_out, 1.0f / n_out);
    } else {
        float* out   = (float*)d_out;
        float* stats = (float*)d_ws;
        hipMemsetAsync(d_out, 0, (size_t)out_size * sizeof(float), stream);
        hipMemsetAsync(d_ws, 0, 2 * C_OUT * sizeof(float), stream);

        scatter_gemm_f32_kernel<<<grid_g, 256, 0, stream>>>(feats, W, in_idx, out_idx, out, P);
        bn_stats_f32_kernel<<<1024, 256, 0, stream>>>(out, stats, n_out);
        bn_apply_f32_kernel<<<2048, 256, 0, stream>>>(out, stats, gamma, beta, n_out, 1.0f / n_out);
    }
}